// Round 15
// baseline (232.612 us; speedup 1.0000x reference)
//
#include <hip/hip_runtime.h>
#include <math.h>

// n=2, C=288, h=w=64 -> hw=4096; kv stride 2 -> 32x32 -> pkv=1024; M=9 heads, d=32
#define NB     2
#define CDIM   288
#define HW     4096
#define PKV    1024
#define MHEAD  9
#define DHEAD  32

typedef __attribute__((ext_vector_type(8))) short bf16x8;
typedef __attribute__((ext_vector_type(4))) float f32x4;

__device__ inline unsigned short f2bf(float x) {
    unsigned int u = __float_as_uint(x);
    u = (u + 0x7fffu + ((u >> 16) & 1u)) >> 16;
    return (unsigned short)u;
}

// ---------------------------------------------------------------------------
// Fragment-major tile (16 rows r, 32 k): elem(r,k) = ((r&15)+16*(k>>3))*8 + (k&7)
//  WF (A-side, rows=o, k=c): tiles (ot,cc) -> (ot*9+cc)*512
//  XF (B-side, rows=j, k=c): per n, (jt,cc) -> (jt*9+cc)*512
//  KF (B-side, rows=p, k=d): per (n,m), pt -> pt*512
//  VF (B-side, rows=o, k=p): per n, (ot,pc) -> (ot*32+pc)*512
//  FXb/FYb (B-side, rows=dif[128 padded], k=d): per m, tile t -> (m*8+t)*512

// ---------------------------------------------------------------------------
// prep: fused xtransF (float4) + wtrans + wcvtF + meanx
__global__ __launch_bounds__(256) void prep(const float* __restrict__ X,
        const float* __restrict__ Wq, const float* __restrict__ Wk,
        const float* __restrict__ Wv, const float* __restrict__ Wproj,
        const float* __restrict__ Wx, const float* __restrict__ Wy,
        unsigned short* __restrict__ XF, unsigned short* __restrict__ WFq,
        unsigned short* __restrict__ WFk, unsigned short* __restrict__ WFv,
        unsigned short* __restrict__ WFp, float* __restrict__ WTx,
        float* __restrict__ WTy, float* __restrict__ MX) {
    __shared__ float t32[32][133];
    __shared__ float t16[16][17];
    __shared__ float red[4];
    int b = blockIdx.x;
    int tid = threadIdx.x;
    if (b < 576) {
        // ---- xtransF: 128j x 32c tile, float4 loads
        int bx = b % 32, by = (b / 32) % 9, n = b / 288;
        int j0 = bx * 128, c0 = by * 32;
        int c = tid >> 3, f = tid & 7;
        const float* src = &X[((size_t)n * CDIM + c0 + c) * HW + j0];
#pragma unroll
        for (int l = 0; l < 4; ++l) {
            float4 v = *(const float4*)&src[(f + l * 8) * 4];
            *(float4*)&t32[c][(f + l * 8) * 4] = v;
        }
        __syncthreads();
        int cc = c0 >> 5;
#pragma unroll
        for (int l = 0; l < 4; ++l) {
            int g = l * 256 + tid;           // 0..1023
            int s = g >> 7;                  // j-subtile 0..7
            int w = g & 127;
            int lane = w >> 1, e0 = (w & 1) * 4;
            int jl = s * 16 + (lane & 15);
            int cb = (lane >> 4) * 8 + e0;
            unsigned int w0 = f2bf(t32[cb + 0][jl]) | ((unsigned int)f2bf(t32[cb + 1][jl]) << 16);
            unsigned int w1 = f2bf(t32[cb + 2][jl]) | ((unsigned int)f2bf(t32[cb + 3][jl]) << 16);
            int jt = (j0 >> 4) + s;
            unsigned short* O = XF + (size_t)n * HW * CDIM + ((size_t)jt * 9 + cc) * 512 + lane * 8 + e0;
            uint2 pk = { w0, w1 };
            *(uint2*)O = pk;
        }
    } else if (b < 900) {
        // ---- wtrans: Wx/Wy (288x144) -> WT (144x288)
        int u = b - 576;
        int bx = u % 9, by = (u / 9) % 18, bz = u / 162;
        const float* W = bz ? Wy : Wx;
        float* WT      = bz ? WTy : WTx;
        int f0 = bx * 16, o0 = by * 16;
        int tx = tid & 15, ty = tid >> 4;
        t16[ty][tx] = W[(o0 + ty) * 144 + f0 + tx];
        __syncthreads();
        WT[(f0 + ty) * 288 + o0 + tx] = t16[tx][ty];
    } else if (b < 1062) {
        // ---- wcvtF: 4 weight matrices -> fragment-major bf16 (4 x 64 lanes)
        int t = b - 900;                  // 162 tiles
        int sub = tid >> 6, lane = tid & 63;
        int ot = t / 9, cc = t % 9;
        const float* W = (sub == 0) ? Wq : (sub == 1) ? Wk : (sub == 2) ? Wv : Wproj;
        unsigned short* O = ((sub == 0) ? WFq : (sub == 1) ? WFk : (sub == 2) ? WFv : WFp)
                            + (size_t)t * 512;
        int o  = ot * 16 + (lane & 15);
        int c0 = cc * 32 + (lane >> 4) * 8;
        const float* src = W + (size_t)o * CDIM + c0;
        float4 f0 = *(const float4*)src, f1 = *(const float4*)(src + 4);
        unsigned int v0 = f2bf(f0.x) | ((unsigned int)f2bf(f0.y) << 16);
        unsigned int v1 = f2bf(f0.z) | ((unsigned int)f2bf(f0.w) << 16);
        unsigned int v2 = f2bf(f1.x) | ((unsigned int)f2bf(f1.y) << 16);
        unsigned int v3 = f2bf(f1.z) | ((unsigned int)f2bf(f1.w) << 16);
        uint4 pk = { v0, v1, v2, v3 };
        *(uint4*)(O + lane * 8) = pk;
    } else {
        // ---- meanx
        int bid = b - 1062;               // 576
        const float* xr = X + (size_t)bid * HW;
        float s = 0.f;
        for (int j = tid; j < HW; j += 256) s += xr[j];
        for (int off = 32; off > 0; off >>= 1) s += __shfl_xor(s, off, 64);
        if ((tid & 63) == 0) red[tid >> 6] = s;
        __syncthreads();
        if (tid == 0) MX[bid] = (red[0] + red[1] + red[2] + red[3]) * (1.f / 4096.f);
    }
}

// ---------------------------------------------------------------------------
// mid: fused pff (bf16 fragment-major F tables) + mixw2 (+pad-zeroing) + qkv.
__global__ __launch_bounds__(256) void mid(
        const float* __restrict__ WTx, const float* __restrict__ WTy,
        unsigned short* __restrict__ FXb, unsigned short* __restrict__ FYb,
        const float* __restrict__ Wq, const float* __restrict__ MX,
        const float* __restrict__ Wc, const float* __restrict__ bc,
        float* __restrict__ MIXW,
        const unsigned short* __restrict__ WFq, const unsigned short* __restrict__ WFk,
        const unsigned short* __restrict__ WFv, const unsigned short* __restrict__ XF,
        unsigned short* __restrict__ Qf, unsigned short* __restrict__ KF,
        unsigned short* __restrict__ VF) {
    __shared__ float emb[144];
    __shared__ float ctx_s[NB * CDIM];
    __shared__ float lg[18];
    __shared__ __attribute__((aligned(16))) unsigned short tr[4][32][40];
    int b = blockIdx.x;
    int tid = threadIdx.x;

    if (b < 252) {
        int axis = b / 126;
        int dif  = b % 126;
        float diff = (float)(dif - 62);
        if (tid < 72) {
            float dm = expf(6.9077552789821368f * ((float)tid * (1.f / 72.f)));
            float t  = diff / dm;
            emb[tid]      = sinf(t);
            emb[72 + tid] = cosf(t);
        }
        __syncthreads();
        const float* WT = axis ? WTy : WTx;
        unsigned short* F = axis ? FYb : FXb;
        for (int o = tid; o < CDIM; o += 256) {
            float s = 0.f;
#pragma unroll 8
            for (int f = 0; f < 144; ++f) s += emb[f] * WT[f * 288 + o];
            int m = o >> 5, d = o & 31;
            F[(size_t)(m * 8 + (dif >> 4)) * 512 + ((dif & 15) + 16 * (d >> 3)) * 8 + (d & 7)]
                = f2bf(s * 0.70710678118654752f);
        }
    } else if (b == 252) {
        for (int idx = tid; idx < 1152; idx += 256) {
            int d = idx & 31, rr = (idx >> 5) & 1, mm = (idx >> 6) % 9, ax = idx / 576;
            int dif = 126 + rr;
            unsigned short* F = ax ? FYb : FXb;
            F[(size_t)(mm * 8 + 7) * 512 + ((dif & 15) + 16 * (d >> 3)) * 8 + (d & 7)] = 0;
        }
        for (int p = tid; p < NB * CDIM; p += 256) {
            int n = p / CDIM, o = p % CDIM;
            const float* wr = Wq + (size_t)o * CDIM;
            const float* mx = MX + n * CDIM;
            float s = 0.f;
            for (int c = 0; c < CDIM; c += 4) {
                float4 w4 = *(const float4*)&wr[c];
                float4 m4 = *(const float4*)&mx[c];
                s += w4.x * m4.x + w4.y * m4.y + w4.z * m4.z + w4.w * m4.w;
            }
            ctx_s[p] = s;
        }
        __syncthreads();
        if (tid < 18) {
            int n = tid / 9, j = tid % 9;
            float s = bc[j];
            for (int o = 0; o < CDIM; ++o) s += ctx_s[n * CDIM + o] * Wc[j * CDIM + o];
            lg[tid] = s;
        }
        __syncthreads();
        if (tid < 2) {
            float mx = -1e30f;
            for (int j = 0; j < 9; ++j) mx = fmaxf(mx, lg[tid * 9 + j]);
            float e[9], sm = 0.f;
            for (int j = 0; j < 9; ++j) { e[j] = __expf(lg[tid * 9 + j] - mx); sm += e[j]; }
            for (int j = 0; j < 9; ++j) MIXW[tid * 9 + j] = e[j] / sm;
        }
    } else {
        int bx = b - 253;
        int gx = bx % 40;
        int m  = (bx / 40) % 9;
        int n  = bx / 360;
        int wv = tid >> 6, lane = tid & 63;
        int lq = lane & 15, quad = lane >> 4;
        if (gx < 32) {
            int j0 = gx * 128;
            int jw = j0 + wv * 32;
            const unsigned short* Wb = WFq + ((size_t)(m * 2) * 9) * 512 + lane * 8;
            const unsigned short* Xb = XF + (size_t)n * HW * CDIM + ((size_t)(jw >> 4) * 9) * 512 + lane * 8;
            f32x4 acc[2][2] = {};
#pragma unroll
            for (int cc = 0; cc < 9; ++cc) {
                bf16x8 a0 = *(const bf16x8*)(Wb + (size_t)cc * 512);
                bf16x8 a1 = *(const bf16x8*)(Wb + (size_t)(9 + cc) * 512);
                bf16x8 b0 = *(const bf16x8*)(Xb + (size_t)cc * 512);
                bf16x8 b1 = *(const bf16x8*)(Xb + (size_t)(9 + cc) * 512);
                acc[0][0] = __builtin_amdgcn_mfma_f32_16x16x32_bf16(a0, b0, acc[0][0], 0, 0, 0);
                acc[0][1] = __builtin_amdgcn_mfma_f32_16x16x32_bf16(a0, b1, acc[0][1], 0, 0, 0);
                acc[1][0] = __builtin_amdgcn_mfma_f32_16x16x32_bf16(a1, b0, acc[1][0], 0, 0, 0);
                acc[1][1] = __builtin_amdgcn_mfma_f32_16x16x32_bf16(a1, b1, acc[1][1], 0, 0, 0);
            }
#pragma unroll
            for (int oi = 0; oi < 2; ++oi)
#pragma unroll
                for (int ji = 0; ji < 2; ++ji)
#pragma unroll
                    for (int r = 0; r < 4; ++r)
                        tr[wv][ji * 16 + lq][oi * 16 + quad * 4 + r] = f2bf(acc[oi][ji][r]);
            int jl = lane & 31, half = lane >> 5;
            bf16x8 v0 = *(const bf16x8*)&tr[wv][jl][half * 16];
            bf16x8 v1 = *(const bf16x8*)&tr[wv][jl][half * 16 + 8];
            unsigned short* Qm = Qf + ((size_t)(n * MHEAD + m) * HW + jw + jl) * 32 + half * 16;
            *(bf16x8*)Qm = v0;
            *(bf16x8*)(Qm + 8) = v1;
        } else {
            int p0 = (gx - 32) * 128;
            int pw = p0 + wv * 32;
            const unsigned short* XFn = XF + (size_t)n * HW * CDIM;
            size_t bidx[2];
#pragma unroll
            for (int pi = 0; pi < 2; ++pi) {
                int p   = pw + pi * 16 + lq;
                int pos = ((p >> 5) << 7) + ((p & 31) << 1);
                bidx[pi] = ((size_t)(pos >> 4) * 9) * 512 + ((pos & 15) + 16 * quad) * 8;
            }
            const unsigned short* Wkb = WFk + ((size_t)(m * 2) * 9) * 512 + lane * 8;
            const unsigned short* Wvb = WFv + ((size_t)(m * 2) * 9) * 512 + lane * 8;
            f32x4 ak[2][2] = {}, av[2][2] = {};
#pragma unroll
            for (int cc = 0; cc < 9; ++cc) {
                bf16x8 a0k = *(const bf16x8*)(Wkb + (size_t)cc * 512);
                bf16x8 a1k = *(const bf16x8*)(Wkb + (size_t)(9 + cc) * 512);
                bf16x8 a0v = *(const bf16x8*)(Wvb + (size_t)cc * 512);
                bf16x8 a1v = *(const bf16x8*)(Wvb + (size_t)(9 + cc) * 512);
                bf16x8 b0  = *(const bf16x8*)(XFn + bidx[0] + (size_t)cc * 512);
                bf16x8 b1  = *(const bf16x8*)(XFn + bidx[1] + (size_t)cc * 512);
                ak[0][0] = __builtin_amdgcn_mfma_f32_16x16x32_bf16(a0k, b0, ak[0][0], 0, 0, 0);
                ak[0][1] = __builtin_amdgcn_mfma_f32_16x16x32_bf16(a0k, b1, ak[0][1], 0, 0, 0);
                ak[1][0] = __builtin_amdgcn_mfma_f32_16x16x32_bf16(a1k, b0, ak[1][0], 0, 0, 0);
                ak[1][1] = __builtin_amdgcn_mfma_f32_16x16x32_bf16(a1k, b1, ak[1][1], 0, 0, 0);
                av[0][0] = __builtin_amdgcn_mfma_f32_16x16x32_bf16(a0v, b0, av[0][0], 0, 0, 0);
                av[0][1] = __builtin_amdgcn_mfma_f32_16x16x32_bf16(a0v, b1, av[0][1], 0, 0, 0);
                av[1][0] = __builtin_amdgcn_mfma_f32_16x16x32_bf16(a1v, b0, av[1][0], 0, 0, 0);
                av[1][1] = __builtin_amdgcn_mfma_f32_16x16x32_bf16(a1v, b1, av[1][1], 0, 0, 0);
            }
#pragma unroll
            for (int oi = 0; oi < 2; ++oi)
#pragma unroll
                for (int pi = 0; pi < 2; ++pi)
#pragma unroll
                    for (int r = 0; r < 4; ++r)
                        tr[wv][pi * 16 + lq][oi * 16 + quad * 4 + r] = f2bf(ak[oi][pi][r]);
            unsigned short* KFm = KF + (size_t)(n * MHEAD + m) * (PKV * 32);
#pragma unroll
            for (int pi = 0; pi < 2; ++pi) {
                bf16x8 v = *(const bf16x8*)&tr[wv][pi * 16 + lq][quad * 8];
                *(bf16x8*)(KFm + (size_t)((pw >> 4) + pi) * 512 + lane * 8) = v;
            }
#pragma unroll
            for (int oi = 0; oi < 2; ++oi)
#pragma unroll
                for (int pi = 0; pi < 2; ++pi)
#pragma unroll
                    for (int r = 0; r < 4; ++r)
                        tr[wv][oi * 16 + quad * 4 + r][pi * 16 + lq] = f2bf(av[oi][pi][r]);
            unsigned short* VFn = VF + (size_t)n * CDIM * PKV;
#pragma unroll
            for (int oi = 0; oi < 2; ++oi) {
                bf16x8 v = *(const bf16x8*)&tr[wv][oi * 16 + lq][quad * 8];
                *(bf16x8*)(VFn + (size_t)((m * 2 + oi) * 32 + (pw >> 5)) * 512 + lane * 8) = v;
            }
        }
    }
}

// ---------------------------------------------------------------------------
// attn_fused4b: round-11 fused4 (2 barriers/head, inline denominators,
// vectorized ws reads, Mt/R LDS union) with __launch_bounds__(512,6) to
// request 3 blocks/CU (LDS 3x44.5KB = 133KB <= 160KB; VGPR cap ~85 >= 64 used).
__global__ __launch_bounds__(512, 6) void attn_fused4b(
        const unsigned short* __restrict__ Qf, const unsigned short* __restrict__ KF,
        const unsigned short* __restrict__ VF, const unsigned short* __restrict__ WFp,
        const unsigned short* __restrict__ FXb, const unsigned short* __restrict__ FYb,
        const float* __restrict__ MIXW, const float* __restrict__ bproj,
        const float* __restrict__ x, const float* __restrict__ gamma,
        float* __restrict__ OUT) {
    int n    = blockIdx.x >> 8;
    int i0   = (blockIdx.x & 255) * 16;
    int tid  = threadIdx.x;
    int wv   = tid >> 6;          // 0..7
    int lane = tid & 63;
    int lq   = lane & 15;
    int quad = lane >> 4;

    int bx_t = (i0 & 63) >> 4;
    int h    = i0 >> 6;
    int by_t = h >> 4;
    int dh   = h & 15;

    // Rx (16x82 f32) + Ry (16x82 f32) unioned with Mt (16x296 bf16)
    __shared__ __attribute__((aligned(16))) unsigned char RM[10752];
    float (*Rx_s)[82] = (float (*)[82])RM;
    float (*Ry_s)[82] = (float (*)[82])(RM + 5248);
    unsigned short (*Mt)[296] = (unsigned short (*)[296])RM;     // 9472 B <= 10752
    __shared__ __attribute__((aligned(16))) float ws_s[16][8];
    __shared__ __attribute__((aligned(16))) unsigned short tr[16][1032];

    float mixed[8][4];
#pragma unroll
    for (int t = 0; t < 8; ++t)
#pragma unroll
        for (int j = 0; j < 4; ++j) mixed[t][j] = 0.f;

    for (int m = 0; m < MHEAD; ++m) {
        const unsigned short* Qm  = Qf + ((size_t)(n * MHEAD + m) * HW + i0) * 32;
        const unsigned short* KmF = KF + (size_t)(n * MHEAD + m) * (PKV * 32);
        bf16x8 afrag = *(const bf16x8*)(Qm + (size_t)lq * 32 + quad * 8);

        // ---- R phase: Rx[q][r]=Q.FX[w0+r], Ry[q][r]=Q.FY[h0+r]; 10 tiles / 8 waves
        if (wv < 5) {
            bf16x8 bR = *(const bf16x8*)(FXb + (size_t)(m * 8 + bx_t + wv) * 512 + lane * 8);
            f32x4 r = (f32x4){0.f, 0.f, 0.f, 0.f};
            r = __builtin_amdgcn_mfma_f32_16x16x32_bf16(afrag, bR, r, 0, 0, 0);
#pragma unroll
            for (int reg = 0; reg < 4; ++reg)
                Rx_s[quad * 4 + reg][wv * 16 + lq] = r[reg];
        } else {
            bf16x8 bR = *(const bf16x8*)(FYb + (size_t)(m * 8 + by_t + (wv - 5)) * 512 + lane * 8);
            f32x4 r = (f32x4){0.f, 0.f, 0.f, 0.f};
            r = __builtin_amdgcn_mfma_f32_16x16x32_bf16(afrag, bR, r, 0, 0, 0);
#pragma unroll
            for (int reg = 0; reg < 4; ++reg)
                Ry_s[quad * 4 + reg][(wv - 5) * 16 + lq] = r[reg];
        }
        if (wv < 2) {
            bf16x8 bR = *(const bf16x8*)(FYb + (size_t)(m * 8 + by_t + 3 + wv) * 512 + lane * 8);
            f32x4 r = (f32x4){0.f, 0.f, 0.f, 0.f};
            r = __builtin_amdgcn_mfma_f32_16x16x32_bf16(afrag, bR, r, 0, 0, 0);
#pragma unroll
            for (int reg = 0; reg < 4; ++reg)
                Ry_s[quad * 4 + reg][(3 + wv) * 16 + lq] = r[reg];
        }
        __syncthreads();   // B1: R tables ready

        // ---- QK^T: this wave's 128 kv
        bf16x8 kf[8];
#pragma unroll
        for (int t = 0; t < 8; ++t)
            kf[t] = *(const bf16x8*)(KmF + (size_t)(wv * 8 + t) * 512 + lane * 8);
        f32x4 acc[8];
#pragma unroll
        for (int t = 0; t < 8; ++t) acc[t] = (f32x4){0.f, 0.f, 0.f, 0.f};
#pragma unroll
        for (int t = 0; t < 8; ++t)
            acc[t] = __builtin_amdgcn_mfma_f32_16x16x32_bf16(afrag, kf[t], acc[t], 0, 0, 0);

        float exA[4], exB[4];
#pragma unroll
        for (int j = 0; j < 4; ++j) {
            int q = quad * 4 + j;
            exA[j] = Rx_s[q][q + 62 - 2 * lq];        // v = lq
            exB[j] = Rx_s[q][q + 30 - 2 * lq];        // v = lq + 16
        }

        float rs[4] = {0.f, 0.f, 0.f, 0.f};
#pragma unroll
        for (int tp = 0; tp < 4; ++tp) {
            int u = wv * 4 + tp;
            float ey[4];
#pragma unroll
            for (int j = 0; j < 4; ++j) ey[j] = Ry_s[quad * 4 + j][dh + 62 - 2 * u];
#pragma unroll
            for (int half = 0; half < 2; ++half) {
                int t = tp * 2 + half;
#pragma unroll
                for (int j = 0; j < 4; ++j) {
                    float e = __expf(acc[t][j] + (half ? exB[j] : exA[j]) + ey[j]);
                    rs[j] += e;
                    acc[t][j] = e;
                }
            }
        }
#pragma unroll
        for (int j = 0; j < 4; ++j) {
            rs[j] += __shfl_xor(rs[j], 1, 64);
            rs[j] += __shfl_xor(rs[j], 2, 64);
            rs[j] += __shfl_xor(rs[j], 4, 64);
            rs[j] += __shfl_xor(rs[j], 8, 64);
        }
        if (lq == 0) {
#pragma unroll
            for (int j = 0; j < 4; ++j) ws_s[quad * 4 + j][wv] = rs[j];
        }
        __syncthreads();   // B2: ws ready; also fences this head's R reads

        float wm = MIXW[n * MHEAD + m];
#pragma unroll
        for (int j = 0; j < 4; ++j) {
            int q = quad * 4 + j;
            float4 w0 = *(const float4*)&ws_s[q][0];
            float4 w1 = *(const float4*)&ws_s[q][4];
            float lt = (w0.x + w0.y) + (w0.z + w0.w) + (w1.x + w1.y) + (w1.z + w1.w);
            float fct = wm / lt;
#pragma unroll
            for (int t = 0; t < 8; ++t) mixed[t][j] += acc[t][j] * fct;
        }
    }

    // --- P (mixed attn) -> LDS [i][p]
#pragma unroll
    for (int t = 0; t < 8; ++t)
#pragma unroll
        for (int j = 0; j < 4; ++j)
            tr[quad * 4 + j][wv * 128 + t * 16 + lq] = f2bf(mixed[t][j]);
    __syncthreads();   // fences last R reads too -> Mt may overwrite RM

    // --- PV: O(16x288) = P(16x1024) @ V^T; wave wv owns o-tiles {wv, wv+8, wv+16<18}
    const unsigned short* VFn = VF + (size_t)n * CDIM * PKV;
    f32x4 accpv[3];
#pragma unroll
    for (int idx = 0; idx < 3; ++idx) accpv[idx] = (f32x4){0.f, 0.f, 0.f, 0.f};
#pragma unroll 4
    for (int pc = 0; pc < 32; ++pc) {
        bf16x8 pf = *(const bf16x8*)&tr[lq][pc * 32 + quad * 8];
#pragma unroll
        for (int idx = 0; idx < 3; ++idx) {
            int ot = wv + idx * 8;
            if (ot < 18) {
                bf16x8 vf = *(const bf16x8*)(VFn + (size_t)(ot * 32 + pc) * 512 + lane * 8);
                accpv[idx] = __builtin_amdgcn_mfma_f32_16x16x32_bf16(pf, vf, accpv[idx], 0, 0, 0);
            }
        }
    }
#pragma unroll
    for (int idx = 0; idx < 3; ++idx) {
        int ot = wv + idx * 8;
        if (ot < 18) {
#pragma unroll
            for (int r = 0; r < 4; ++r)
                Mt[quad * 4 + r][ot * 16 + lq] = f2bf(accpv[idx][r]);
        }
    }
    __syncthreads();

    // --- proj: OUT(288x16) = Wproj @ MID + bias, gamma, residual
    float g = gamma[0];
#pragma unroll
    for (int idx = 0; idx < 3; ++idx) {
        int ot = wv + idx * 8;
        if (ot >= 18) continue;
        f32x4 acc = (f32x4){0.f, 0.f, 0.f, 0.f};
#pragma unroll
        for (int cc = 0; cc < 9; ++cc) {
            bf16x8 af = *(const bf16x8*)(WFp + (size_t)(ot * 9 + cc) * 512 + lane * 8);
            bf16x8 bfm = *(const bf16x8*)&Mt[lq][cc * 32 + quad * 8];
            acc = __builtin_amdgcn_mfma_f32_16x16x32_bf16(af, bfm, acc, 0, 0, 0);
        }
#pragma unroll
        for (int r = 0; r < 4; ++r) {
            int o = ot * 16 + quad * 4 + r;
            size_t id = ((size_t)(n * CDIM) + o) * HW + i0 + lq;
            OUT[id] = g * (acc[r] + bproj[o]) + x[id];
        }
    }
}

// ---------------------------------------------------------------------------
extern "C" void kernel_launch(void* const* d_in, const int* in_sizes, int n_in,
                              void* d_out, int out_size, void* d_ws, size_t ws_size,
                              hipStream_t stream) {
    const float* x     = (const float*)d_in[0];
    const float* Wq    = (const float*)d_in[1];
    const float* Wk    = (const float*)d_in[2];
    const float* Wv    = (const float*)d_in[3];
    const float* Wx    = (const float*)d_in[4];
    const float* Wy    = (const float*)d_in[5];
    const float* Wproj = (const float*)d_in[6];
    const float* bproj = (const float*)d_in[7];
    const float* Wc    = (const float*)d_in[8];
    const float* bc    = (const float*)d_in[9];
    const float* gamma = (const float*)d_in[10];
    float* out = (float*)d_out;

    float* ws = (float*)d_ws;
    size_t off = 0;
    unsigned short* Qf  = (unsigned short*)(ws + off); off += (size_t)NB * MHEAD * HW * 32 / 2;
    unsigned short* KF  = (unsigned short*)(ws + off); off += (size_t)NB * MHEAD * PKV * 32 / 2;
    unsigned short* VF  = (unsigned short*)(ws + off); off += (size_t)NB * CDIM * PKV / 2;
    unsigned short* WFq = (unsigned short*)(ws + off); off += (size_t)CDIM * CDIM / 2;
    unsigned short* WFk = (unsigned short*)(ws + off); off += (size_t)CDIM * CDIM / 2;
    unsigned short* WFv = (unsigned short*)(ws + off); off += (size_t)CDIM * CDIM / 2;
    unsigned short* WFp = (unsigned short*)(ws + off); off += (size_t)CDIM * CDIM / 2;
    unsigned short* XF  = (unsigned short*)(ws + off); off += (size_t)NB * HW * CDIM / 2;
    float* WTx  = ws + off; off += 144 * 288;
    float* WTy  = ws + off; off += 144 * 288;
    unsigned short* FXb = (unsigned short*)(ws + off); off += (size_t)MHEAD * 8 * 512 / 2;
    unsigned short* FYb = (unsigned short*)(ws + off); off += (size_t)MHEAD * 8 * 512 / 2;
    float* MX   = ws + off; off += NB * CDIM;
    float* MIXW = ws + off; off += 32;

    prep<<<1638, 256, 0, stream>>>(x, Wq, Wk, Wv, Wproj, Wx, Wy,
                                   XF, WFq, WFk, WFv, WFp, WTx, WTy, MX);
    mid<<<973, 256, 0, stream>>>(WTx, WTy, FXb, FYb, Wq, MX, Wc, bc, MIXW,
                                 WFq, WFk, WFv, XF, Qf, KF, VF);
    attn_fused4b<<<NB * HW / 16, 512, 0, stream>>>(Qf, KF, VF, WFp, FXb, FYb, MIXW,
                                                   bproj, x, gamma, out);
}

// Round 16
// 177.402 us; speedup vs baseline: 1.3112x; 1.3112x over previous
//
#include <hip/hip_runtime.h>
#include <math.h>

// n=2, C=288, h=w=64 -> hw=4096; kv stride 2 -> 32x32 -> pkv=1024; M=9 heads, d=32
#define NB     2
#define CDIM   288
#define HW     4096
#define PKV    1024
#define MHEAD  9
#define DHEAD  32

typedef __attribute__((ext_vector_type(8))) short bf16x8;
typedef __attribute__((ext_vector_type(4))) float f32x4;

__device__ inline unsigned short f2bf(float x) {
    unsigned int u = __float_as_uint(x);
    u = (u + 0x7fffu + ((u >> 16) & 1u)) >> 16;
    return (unsigned short)u;
}

// ---------------------------------------------------------------------------
// Fragment-major tile (16 rows r, 32 k): elem(r,k) = ((r&15)+16*(k>>3))*8 + (k&7)
//  WF (A-side, rows=o, k=c): tiles (ot,cc) -> (ot*9+cc)*512
//  XF (B-side, rows=j, k=c): per n, (jt,cc) -> (jt*9+cc)*512
//  KF (B-side, rows=p, k=d): per (n,m), pt -> pt*512
//  VF (B-side, rows=o, k=p): per n, (ot,pc) -> (ot*32+pc)*512
//  FXb/FYb (B-side, rows=dif[128 padded], k=d): per m, tile t -> (m*8+t)*512

// ---------------------------------------------------------------------------
// prep: fused xtransF (float4) + wtrans + wcvtF + meanx
__global__ __launch_bounds__(256) void prep(const float* __restrict__ X,
        const float* __restrict__ Wq, const float* __restrict__ Wk,
        const float* __restrict__ Wv, const float* __restrict__ Wproj,
        const float* __restrict__ Wx, const float* __restrict__ Wy,
        unsigned short* __restrict__ XF, unsigned short* __restrict__ WFq,
        unsigned short* __restrict__ WFk, unsigned short* __restrict__ WFv,
        unsigned short* __restrict__ WFp, float* __restrict__ WTx,
        float* __restrict__ WTy, float* __restrict__ MX) {
    __shared__ float t32[32][133];
    __shared__ float t16[16][17];
    __shared__ float red[4];
    int b = blockIdx.x;
    int tid = threadIdx.x;
    if (b < 576) {
        // ---- xtransF: 128j x 32c tile, float4 loads
        int bx = b % 32, by = (b / 32) % 9, n = b / 288;
        int j0 = bx * 128, c0 = by * 32;
        int c = tid >> 3, f = tid & 7;
        const float* src = &X[((size_t)n * CDIM + c0 + c) * HW + j0];
#pragma unroll
        for (int l = 0; l < 4; ++l) {
            float4 v = *(const float4*)&src[(f + l * 8) * 4];
            *(float4*)&t32[c][(f + l * 8) * 4] = v;
        }
        __syncthreads();
        int cc = c0 >> 5;
#pragma unroll
        for (int l = 0; l < 4; ++l) {
            int g = l * 256 + tid;           // 0..1023
            int s = g >> 7;                  // j-subtile 0..7
            int w = g & 127;
            int lane = w >> 1, e0 = (w & 1) * 4;
            int jl = s * 16 + (lane & 15);
            int cb = (lane >> 4) * 8 + e0;
            unsigned int w0 = f2bf(t32[cb + 0][jl]) | ((unsigned int)f2bf(t32[cb + 1][jl]) << 16);
            unsigned int w1 = f2bf(t32[cb + 2][jl]) | ((unsigned int)f2bf(t32[cb + 3][jl]) << 16);
            int jt = (j0 >> 4) + s;
            unsigned short* O = XF + (size_t)n * HW * CDIM + ((size_t)jt * 9 + cc) * 512 + lane * 8 + e0;
            uint2 pk = { w0, w1 };
            *(uint2*)O = pk;
        }
    } else if (b < 900) {
        // ---- wtrans: Wx/Wy (288x144) -> WT (144x288)
        int u = b - 576;
        int bx = u % 9, by = (u / 9) % 18, bz = u / 162;
        const float* W = bz ? Wy : Wx;
        float* WT      = bz ? WTy : WTx;
        int f0 = bx * 16, o0 = by * 16;
        int tx = tid & 15, ty = tid >> 4;
        t16[ty][tx] = W[(o0 + ty) * 144 + f0 + tx];
        __syncthreads();
        WT[(f0 + ty) * 288 + o0 + tx] = t16[tx][ty];
    } else if (b < 1062) {
        // ---- wcvtF: 4 weight matrices -> fragment-major bf16 (4 x 64 lanes)
        int t = b - 900;                  // 162 tiles
        int sub = tid >> 6, lane = tid & 63;
        int ot = t / 9, cc = t % 9;
        const float* W = (sub == 0) ? Wq : (sub == 1) ? Wk : (sub == 2) ? Wv : Wproj;
        unsigned short* O = ((sub == 0) ? WFq : (sub == 1) ? WFk : (sub == 2) ? WFv : WFp)
                            + (size_t)t * 512;
        int o  = ot * 16 + (lane & 15);
        int c0 = cc * 32 + (lane >> 4) * 8;
        const float* src = W + (size_t)o * CDIM + c0;
        float4 f0 = *(const float4*)src, f1 = *(const float4*)(src + 4);
        unsigned int v0 = f2bf(f0.x) | ((unsigned int)f2bf(f0.y) << 16);
        unsigned int v1 = f2bf(f0.z) | ((unsigned int)f2bf(f0.w) << 16);
        unsigned int v2 = f2bf(f1.x) | ((unsigned int)f2bf(f1.y) << 16);
        unsigned int v3 = f2bf(f1.z) | ((unsigned int)f2bf(f1.w) << 16);
        uint4 pk = { v0, v1, v2, v3 };
        *(uint4*)(O + lane * 8) = pk;
    } else {
        // ---- meanx
        int bid = b - 1062;               // 576
        const float* xr = X + (size_t)bid * HW;
        float s = 0.f;
        for (int j = tid; j < HW; j += 256) s += xr[j];
        for (int off = 32; off > 0; off >>= 1) s += __shfl_xor(s, off, 64);
        if ((tid & 63) == 0) red[tid >> 6] = s;
        __syncthreads();
        if (tid == 0) MX[bid] = (red[0] + red[1] + red[2] + red[3]) * (1.f / 4096.f);
    }
}

// ---------------------------------------------------------------------------
// mid: fused pff (bf16 fragment-major F tables) + mixw2 (+pad-zeroing) + qkv.
__global__ __launch_bounds__(256) void mid(
        const float* __restrict__ WTx, const float* __restrict__ WTy,
        unsigned short* __restrict__ FXb, unsigned short* __restrict__ FYb,
        const float* __restrict__ Wq, const float* __restrict__ MX,
        const float* __restrict__ Wc, const float* __restrict__ bc,
        float* __restrict__ MIXW,
        const unsigned short* __restrict__ WFq, const unsigned short* __restrict__ WFk,
        const unsigned short* __restrict__ WFv, const unsigned short* __restrict__ XF,
        unsigned short* __restrict__ Qf, unsigned short* __restrict__ KF,
        unsigned short* __restrict__ VF) {
    __shared__ float emb[144];
    __shared__ float ctx_s[NB * CDIM];
    __shared__ float lg[18];
    __shared__ __attribute__((aligned(16))) unsigned short tr[4][32][40];
    int b = blockIdx.x;
    int tid = threadIdx.x;

    if (b < 252) {
        int axis = b / 126;
        int dif  = b % 126;
        float diff = (float)(dif - 62);
        if (tid < 72) {
            float dm = expf(6.9077552789821368f * ((float)tid * (1.f / 72.f)));
            float t  = diff / dm;
            emb[tid]      = sinf(t);
            emb[72 + tid] = cosf(t);
        }
        __syncthreads();
        const float* WT = axis ? WTy : WTx;
        unsigned short* F = axis ? FYb : FXb;
        for (int o = tid; o < CDIM; o += 256) {
            float s = 0.f;
#pragma unroll 8
            for (int f = 0; f < 144; ++f) s += emb[f] * WT[f * 288 + o];
            int m = o >> 5, d = o & 31;
            F[(size_t)(m * 8 + (dif >> 4)) * 512 + ((dif & 15) + 16 * (d >> 3)) * 8 + (d & 7)]
                = f2bf(s * 0.70710678118654752f);
        }
    } else if (b == 252) {
        for (int idx = tid; idx < 1152; idx += 256) {
            int d = idx & 31, rr = (idx >> 5) & 1, mm = (idx >> 6) % 9, ax = idx / 576;
            int dif = 126 + rr;
            unsigned short* F = ax ? FYb : FXb;
            F[(size_t)(mm * 8 + 7) * 512 + ((dif & 15) + 16 * (d >> 3)) * 8 + (d & 7)] = 0;
        }
        for (int p = tid; p < NB * CDIM; p += 256) {
            int n = p / CDIM, o = p % CDIM;
            const float* wr = Wq + (size_t)o * CDIM;
            const float* mx = MX + n * CDIM;
            float s = 0.f;
            for (int c = 0; c < CDIM; c += 4) {
                float4 w4 = *(const float4*)&wr[c];
                float4 m4 = *(const float4*)&mx[c];
                s += w4.x * m4.x + w4.y * m4.y + w4.z * m4.z + w4.w * m4.w;
            }
            ctx_s[p] = s;
        }
        __syncthreads();
        if (tid < 18) {
            int n = tid / 9, j = tid % 9;
            float s = bc[j];
            for (int o = 0; o < CDIM; ++o) s += ctx_s[n * CDIM + o] * Wc[j * CDIM + o];
            lg[tid] = s;
        }
        __syncthreads();
        if (tid < 2) {
            float mx = -1e30f;
            for (int j = 0; j < 9; ++j) mx = fmaxf(mx, lg[tid * 9 + j]);
            float e[9], sm = 0.f;
            for (int j = 0; j < 9; ++j) { e[j] = __expf(lg[tid * 9 + j] - mx); sm += e[j]; }
            for (int j = 0; j < 9; ++j) MIXW[tid * 9 + j] = e[j] / sm;
        }
    } else {
        int bx = b - 253;
        int gx = bx % 40;
        int m  = (bx / 40) % 9;
        int n  = bx / 360;
        int wv = tid >> 6, lane = tid & 63;
        int lq = lane & 15, quad = lane >> 4;
        if (gx < 32) {
            int j0 = gx * 128;
            int jw = j0 + wv * 32;
            const unsigned short* Wb = WFq + ((size_t)(m * 2) * 9) * 512 + lane * 8;
            const unsigned short* Xb = XF + (size_t)n * HW * CDIM + ((size_t)(jw >> 4) * 9) * 512 + lane * 8;
            f32x4 acc[2][2] = {};
#pragma unroll
            for (int cc = 0; cc < 9; ++cc) {
                bf16x8 a0 = *(const bf16x8*)(Wb + (size_t)cc * 512);
                bf16x8 a1 = *(const bf16x8*)(Wb + (size_t)(9 + cc) * 512);
                bf16x8 b0 = *(const bf16x8*)(Xb + (size_t)cc * 512);
                bf16x8 b1 = *(const bf16x8*)(Xb + (size_t)(9 + cc) * 512);
                acc[0][0] = __builtin_amdgcn_mfma_f32_16x16x32_bf16(a0, b0, acc[0][0], 0, 0, 0);
                acc[0][1] = __builtin_amdgcn_mfma_f32_16x16x32_bf16(a0, b1, acc[0][1], 0, 0, 0);
                acc[1][0] = __builtin_amdgcn_mfma_f32_16x16x32_bf16(a1, b0, acc[1][0], 0, 0, 0);
                acc[1][1] = __builtin_amdgcn_mfma_f32_16x16x32_bf16(a1, b1, acc[1][1], 0, 0, 0);
            }
#pragma unroll
            for (int oi = 0; oi < 2; ++oi)
#pragma unroll
                for (int ji = 0; ji < 2; ++ji)
#pragma unroll
                    for (int r = 0; r < 4; ++r)
                        tr[wv][ji * 16 + lq][oi * 16 + quad * 4 + r] = f2bf(acc[oi][ji][r]);
            int jl = lane & 31, half = lane >> 5;
            bf16x8 v0 = *(const bf16x8*)&tr[wv][jl][half * 16];
            bf16x8 v1 = *(const bf16x8*)&tr[wv][jl][half * 16 + 8];
            unsigned short* Qm = Qf + ((size_t)(n * MHEAD + m) * HW + jw + jl) * 32 + half * 16;
            *(bf16x8*)Qm = v0;
            *(bf16x8*)(Qm + 8) = v1;
        } else {
            int p0 = (gx - 32) * 128;
            int pw = p0 + wv * 32;
            const unsigned short* XFn = XF + (size_t)n * HW * CDIM;
            size_t bidx[2];
#pragma unroll
            for (int pi = 0; pi < 2; ++pi) {
                int p   = pw + pi * 16 + lq;
                int pos = ((p >> 5) << 7) + ((p & 31) << 1);
                bidx[pi] = ((size_t)(pos >> 4) * 9) * 512 + ((pos & 15) + 16 * quad) * 8;
            }
            const unsigned short* Wkb = WFk + ((size_t)(m * 2) * 9) * 512 + lane * 8;
            const unsigned short* Wvb = WFv + ((size_t)(m * 2) * 9) * 512 + lane * 8;
            f32x4 ak[2][2] = {}, av[2][2] = {};
#pragma unroll
            for (int cc = 0; cc < 9; ++cc) {
                bf16x8 a0k = *(const bf16x8*)(Wkb + (size_t)cc * 512);
                bf16x8 a1k = *(const bf16x8*)(Wkb + (size_t)(9 + cc) * 512);
                bf16x8 a0v = *(const bf16x8*)(Wvb + (size_t)cc * 512);
                bf16x8 a1v = *(const bf16x8*)(Wvb + (size_t)(9 + cc) * 512);
                bf16x8 b0  = *(const bf16x8*)(XFn + bidx[0] + (size_t)cc * 512);
                bf16x8 b1  = *(const bf16x8*)(XFn + bidx[1] + (size_t)cc * 512);
                ak[0][0] = __builtin_amdgcn_mfma_f32_16x16x32_bf16(a0k, b0, ak[0][0], 0, 0, 0);
                ak[0][1] = __builtin_amdgcn_mfma_f32_16x16x32_bf16(a0k, b1, ak[0][1], 0, 0, 0);
                ak[1][0] = __builtin_amdgcn_mfma_f32_16x16x32_bf16(a1k, b0, ak[1][0], 0, 0, 0);
                ak[1][1] = __builtin_amdgcn_mfma_f32_16x16x32_bf16(a1k, b1, ak[1][1], 0, 0, 0);
                av[0][0] = __builtin_amdgcn_mfma_f32_16x16x32_bf16(a0v, b0, av[0][0], 0, 0, 0);
                av[0][1] = __builtin_amdgcn_mfma_f32_16x16x32_bf16(a0v, b1, av[0][1], 0, 0, 0);
                av[1][0] = __builtin_amdgcn_mfma_f32_16x16x32_bf16(a1v, b0, av[1][0], 0, 0, 0);
                av[1][1] = __builtin_amdgcn_mfma_f32_16x16x32_bf16(a1v, b1, av[1][1], 0, 0, 0);
            }
#pragma unroll
            for (int oi = 0; oi < 2; ++oi)
#pragma unroll
                for (int pi = 0; pi < 2; ++pi)
#pragma unroll
                    for (int r = 0; r < 4; ++r)
                        tr[wv][pi * 16 + lq][oi * 16 + quad * 4 + r] = f2bf(ak[oi][pi][r]);
            unsigned short* KFm = KF + (size_t)(n * MHEAD + m) * (PKV * 32);
#pragma unroll
            for (int pi = 0; pi < 2; ++pi) {
                bf16x8 v = *(const bf16x8*)&tr[wv][pi * 16 + lq][quad * 8];
                *(bf16x8*)(KFm + (size_t)((pw >> 4) + pi) * 512 + lane * 8) = v;
            }
#pragma unroll
            for (int oi = 0; oi < 2; ++oi)
#pragma unroll
                for (int pi = 0; pi < 2; ++pi)
#pragma unroll
                    for (int r = 0; r < 4; ++r)
                        tr[wv][oi * 16 + quad * 4 + r][pi * 16 + lq] = f2bf(av[oi][pi][r]);
            unsigned short* VFn = VF + (size_t)n * CDIM * PKV;
#pragma unroll
            for (int oi = 0; oi < 2; ++oi) {
                bf16x8 v = *(const bf16x8*)&tr[wv][oi * 16 + lq][quad * 8];
                *(bf16x8*)(VFn + (size_t)((m * 2 + oi) * 32 + (pw >> 5)) * 512 + lane * 8) = v;
            }
        }
    }
}

// ---------------------------------------------------------------------------
// attn_fused4: round-11 best config (2 barriers/head, inline denominators,
// vectorized ws reads, Mt/R LDS union, __launch_bounds__(512,4)).
__global__ __launch_bounds__(512, 4) void attn_fused4(
        const unsigned short* __restrict__ Qf, const unsigned short* __restrict__ KF,
        const unsigned short* __restrict__ VF, const unsigned short* __restrict__ WFp,
        const unsigned short* __restrict__ FXb, const unsigned short* __restrict__ FYb,
        const float* __restrict__ MIXW, const float* __restrict__ bproj,
        const float* __restrict__ x, const float* __restrict__ gamma,
        float* __restrict__ OUT) {
    int n    = blockIdx.x >> 8;
    int i0   = (blockIdx.x & 255) * 16;
    int tid  = threadIdx.x;
    int wv   = tid >> 6;          // 0..7
    int lane = tid & 63;
    int lq   = lane & 15;
    int quad = lane >> 4;

    int bx_t = (i0 & 63) >> 4;
    int h    = i0 >> 6;
    int by_t = h >> 4;
    int dh   = h & 15;

    // Rx (16x82 f32) + Ry (16x82 f32) unioned with Mt (16x296 bf16)
    __shared__ __attribute__((aligned(16))) unsigned char RM[10752];
    float (*Rx_s)[82] = (float (*)[82])RM;
    float (*Ry_s)[82] = (float (*)[82])(RM + 5248);
    unsigned short (*Mt)[296] = (unsigned short (*)[296])RM;     // 9472 B <= 10752
    __shared__ __attribute__((aligned(16))) float ws_s[16][8];
    __shared__ __attribute__((aligned(16))) unsigned short tr[16][1032];

    float mixed[8][4];
#pragma unroll
    for (int t = 0; t < 8; ++t)
#pragma unroll
        for (int j = 0; j < 4; ++j) mixed[t][j] = 0.f;

    for (int m = 0; m < MHEAD; ++m) {
        const unsigned short* Qm  = Qf + ((size_t)(n * MHEAD + m) * HW + i0) * 32;
        const unsigned short* KmF = KF + (size_t)(n * MHEAD + m) * (PKV * 32);
        bf16x8 afrag = *(const bf16x8*)(Qm + (size_t)lq * 32 + quad * 8);

        // ---- R phase: Rx[q][r]=Q.FX[w0+r], Ry[q][r]=Q.FY[h0+r]; 10 tiles / 8 waves
        if (wv < 5) {
            bf16x8 bR = *(const bf16x8*)(FXb + (size_t)(m * 8 + bx_t + wv) * 512 + lane * 8);
            f32x4 r = (f32x4){0.f, 0.f, 0.f, 0.f};
            r = __builtin_amdgcn_mfma_f32_16x16x32_bf16(afrag, bR, r, 0, 0, 0);
#pragma unroll
            for (int reg = 0; reg < 4; ++reg)
                Rx_s[quad * 4 + reg][wv * 16 + lq] = r[reg];
        } else {
            bf16x8 bR = *(const bf16x8*)(FYb + (size_t)(m * 8 + by_t + (wv - 5)) * 512 + lane * 8);
            f32x4 r = (f32x4){0.f, 0.f, 0.f, 0.f};
            r = __builtin_amdgcn_mfma_f32_16x16x32_bf16(afrag, bR, r, 0, 0, 0);
#pragma unroll
            for (int reg = 0; reg < 4; ++reg)
                Ry_s[quad * 4 + reg][(wv - 5) * 16 + lq] = r[reg];
        }
        if (wv < 2) {
            bf16x8 bR = *(const bf16x8*)(FYb + (size_t)(m * 8 + by_t + 3 + wv) * 512 + lane * 8);
            f32x4 r = (f32x4){0.f, 0.f, 0.f, 0.f};
            r = __builtin_amdgcn_mfma_f32_16x16x32_bf16(afrag, bR, r, 0, 0, 0);
#pragma unroll
            for (int reg = 0; reg < 4; ++reg)
                Ry_s[quad * 4 + reg][(3 + wv) * 16 + lq] = r[reg];
        }
        __syncthreads();   // B1: R tables ready

        // ---- QK^T: this wave's 128 kv
        bf16x8 kf[8];
#pragma unroll
        for (int t = 0; t < 8; ++t)
            kf[t] = *(const bf16x8*)(KmF + (size_t)(wv * 8 + t) * 512 + lane * 8);
        f32x4 acc[8];
#pragma unroll
        for (int t = 0; t < 8; ++t) acc[t] = (f32x4){0.f, 0.f, 0.f, 0.f};
#pragma unroll
        for (int t = 0; t < 8; ++t)
            acc[t] = __builtin_amdgcn_mfma_f32_16x16x32_bf16(afrag, kf[t], acc[t], 0, 0, 0);

        float exA[4], exB[4];
#pragma unroll
        for (int j = 0; j < 4; ++j) {
            int q = quad * 4 + j;
            exA[j] = Rx_s[q][q + 62 - 2 * lq];        // v = lq
            exB[j] = Rx_s[q][q + 30 - 2 * lq];        // v = lq + 16
        }

        float rs[4] = {0.f, 0.f, 0.f, 0.f};
#pragma unroll
        for (int tp = 0; tp < 4; ++tp) {
            int u = wv * 4 + tp;
            float ey[4];
#pragma unroll
            for (int j = 0; j < 4; ++j) ey[j] = Ry_s[quad * 4 + j][dh + 62 - 2 * u];
#pragma unroll
            for (int half = 0; half < 2; ++half) {
                int t = tp * 2 + half;
#pragma unroll
                for (int j = 0; j < 4; ++j) {
                    float e = __expf(acc[t][j] + (half ? exB[j] : exA[j]) + ey[j]);
                    rs[j] += e;
                    acc[t][j] = e;
                }
            }
        }
#pragma unroll
        for (int j = 0; j < 4; ++j) {
            rs[j] += __shfl_xor(rs[j], 1, 64);
            rs[j] += __shfl_xor(rs[j], 2, 64);
            rs[j] += __shfl_xor(rs[j], 4, 64);
            rs[j] += __shfl_xor(rs[j], 8, 64);
        }
        if (lq == 0) {
#pragma unroll
            for (int j = 0; j < 4; ++j) ws_s[quad * 4 + j][wv] = rs[j];
        }
        __syncthreads();   // B2: ws ready; also fences this head's R reads

        float wm = MIXW[n * MHEAD + m];
#pragma unroll
        for (int j = 0; j < 4; ++j) {
            int q = quad * 4 + j;
            float4 w0 = *(const float4*)&ws_s[q][0];
            float4 w1 = *(const float4*)&ws_s[q][4];
            float lt = (w0.x + w0.y) + (w0.z + w0.w) + (w1.x + w1.y) + (w1.z + w1.w);
            float fct = wm / lt;
#pragma unroll
            for (int t = 0; t < 8; ++t) mixed[t][j] += acc[t][j] * fct;
        }
    }

    // --- P (mixed attn) -> LDS [i][p]
#pragma unroll
    for (int t = 0; t < 8; ++t)
#pragma unroll
        for (int j = 0; j < 4; ++j)
            tr[quad * 4 + j][wv * 128 + t * 16 + lq] = f2bf(mixed[t][j]);
    __syncthreads();   // fences last R reads too -> Mt may overwrite RM

    // --- PV: O(16x288) = P(16x1024) @ V^T; wave wv owns o-tiles {wv, wv+8, wv+16<18}
    const unsigned short* VFn = VF + (size_t)n * CDIM * PKV;
    f32x4 accpv[3];
#pragma unroll
    for (int idx = 0; idx < 3; ++idx) accpv[idx] = (f32x4){0.f, 0.f, 0.f, 0.f};
#pragma unroll 4
    for (int pc = 0; pc < 32; ++pc) {
        bf16x8 pf = *(const bf16x8*)&tr[lq][pc * 32 + quad * 8];
#pragma unroll
        for (int idx = 0; idx < 3; ++idx) {
            int ot = wv + idx * 8;
            if (ot < 18) {
                bf16x8 vf = *(const bf16x8*)(VFn + (size_t)(ot * 32 + pc) * 512 + lane * 8);
                accpv[idx] = __builtin_amdgcn_mfma_f32_16x16x32_bf16(pf, vf, accpv[idx], 0, 0, 0);
            }
        }
    }
#pragma unroll
    for (int idx = 0; idx < 3; ++idx) {
        int ot = wv + idx * 8;
        if (ot < 18) {
#pragma unroll
            for (int r = 0; r < 4; ++r)
                Mt[quad * 4 + r][ot * 16 + lq] = f2bf(accpv[idx][r]);
        }
    }
    __syncthreads();

    // --- proj: OUT(288x16) = Wproj @ MID + bias, gamma, residual
    float g = gamma[0];
#pragma unroll
    for (int idx = 0; idx < 3; ++idx) {
        int ot = wv + idx * 8;
        if (ot >= 18) continue;
        f32x4 acc = (f32x4){0.f, 0.f, 0.f, 0.f};
#pragma unroll
        for (int cc = 0; cc < 9; ++cc) {
            bf16x8 af = *(const bf16x8*)(WFp + (size_t)(ot * 9 + cc) * 512 + lane * 8);
            bf16x8 bfm = *(const bf16x8*)&Mt[lq][cc * 32 + quad * 8];
            acc = __builtin_amdgcn_mfma_f32_16x16x32_bf16(af, bfm, acc, 0, 0, 0);
        }
#pragma unroll
        for (int r = 0; r < 4; ++r) {
            int o = ot * 16 + quad * 4 + r;
            size_t id = ((size_t)(n * CDIM) + o) * HW + i0 + lq;
            OUT[id] = g * (acc[r] + bproj[o]) + x[id];
        }
    }
}

// ---------------------------------------------------------------------------
extern "C" void kernel_launch(void* const* d_in, const int* in_sizes, int n_in,
                              void* d_out, int out_size, void* d_ws, size_t ws_size,
                              hipStream_t stream) {
    const float* x     = (const float*)d_in[0];
    const float* Wq    = (const float*)d_in[1];
    const float* Wk    = (const float*)d_in[2];
    const float* Wv    = (const float*)d_in[3];
    const float* Wx    = (const float*)d_in[4];
    const float* Wy    = (const float*)d_in[5];
    const float* Wproj = (const float*)d_in[6];
    const float* bproj = (const float*)d_in[7];
    const float* Wc    = (const float*)d_in[8];
    const float* bc    = (const float*)d_in[9];
    const float* gamma = (const float*)d_in[10];
    float* out = (float*)d_out;

    float* ws = (float*)d_ws;
    size_t off = 0;
    unsigned short* Qf  = (unsigned short*)(ws + off); off += (size_t)NB * MHEAD * HW * 32 / 2;
    unsigned short* KF  = (unsigned short*)(ws + off); off += (size_t)NB * MHEAD * PKV * 32 / 2;
    unsigned short* VF  = (unsigned short*)(ws + off); off += (size_t)NB * CDIM * PKV / 2;
    unsigned short* WFq = (unsigned short*)(ws + off); off += (size_t)CDIM * CDIM / 2;
    unsigned short* WFk = (unsigned short*)(ws + off); off += (size_t)CDIM * CDIM / 2;
    unsigned short* WFv = (unsigned short*)(ws + off); off += (size_t)CDIM * CDIM / 2;
    unsigned short* WFp = (unsigned short*)(ws + off); off += (size_t)CDIM * CDIM / 2;
    unsigned short* XF  = (unsigned short*)(ws + off); off += (size_t)NB * HW * CDIM / 2;
    float* WTx  = ws + off; off += 144 * 288;
    float* WTy  = ws + off; off += 144 * 288;
    unsigned short* FXb = (unsigned short*)(ws + off); off += (size_t)MHEAD * 8 * 512 / 2;
    unsigned short* FYb = (unsigned short*)(ws + off); off += (size_t)MHEAD * 8 * 512 / 2;
    float* MX   = ws + off; off += NB * CDIM;
    float* MIXW = ws + off; off += 32;

    prep<<<1638, 256, 0, stream>>>(x, Wq, Wk, Wv, Wproj, Wx, Wy,
                                   XF, WFq, WFk, WFv, WFp, WTx, WTy, MX);
    mid<<<973, 256, 0, stream>>>(WTx, WTy, FXb, FYb, Wq, MX, Wc, bc, MIXW,
                                 WFq, WFk, WFv, XF, Qf, KF, VF);
    attn_fused4<<<NB * HW / 16, 512, 0, stream>>>(Qf, KF, VF, WFp, FXb, FYb, MIXW,
                                                  bproj, x, gamma, out);
}